// Round 4
// baseline (298.843 us; speedup 1.0000x reference)
//
#include <hip/hip_runtime.h>
#include <hip/hip_bf16.h>

#define NN 100000
#define NE 800000
#define HIDDEN 128
#define NED (2 * NE)            // edge-directions: [0,NE)=fwd(by src), [NE,2NE)=bwd(by dst)
#define BKN 64                  // nodes per bucket
#define NBF 1563                // ceil(NN/BKN)
#define NBUCK (2 * NBF)         // 3126
#define PS 13                   // buckets per thread in part_scatter scan (13*256>=NBUCK)
#define CHUNK 4096              // edges per partition block (LDS fits 2 blocks/CU)
#define PBLK ((NED + CHUNK - 1) / CHUNK)   // 391
#define GC 128                  // rows per gather stage-chunk
#define NTILES 3125             // 100000 / 32 exact

typedef __attribute__((ext_vector_type(8))) short bf16x8;
typedef __attribute__((ext_vector_type(4))) short bf16x4;
typedef __attribute__((ext_vector_type(4))) float f32x4;

__device__ __forceinline__ short f2bf(float f) {
  union { float f; unsigned u; } x; x.f = f;
  unsigned r = x.u + 0x7fffu + ((x.u >> 16) & 1u);   // RNE
  return (short)(r >> 16);
}
__device__ __forceinline__ float bf2f(short s) {
  union { unsigned u; float f; } x;
  x.u = ((unsigned)(unsigned short)s) << 16;
  return x.f;
}

// ---- weights fp32 -> bf16 (order: [0]=Ws_w, [1]=W_w, [2]=Wt_w) ----
__global__ __launch_bounds__(256) void convert_weights(
    const float* __restrict__ m0, const float* __restrict__ m1,
    const float* __restrict__ m2, short* __restrict__ out) {
  int i = blockIdx.x * 256 + threadIdx.x;   // [0, 3*16384)
  int m = i >> 14, j = i & 16383;
  const float* s = (m == 0) ? m0 : (m == 1) ? m1 : m2;
  out[i] = f2bf(s[j]);
}

// ---- h fp32 -> bf16 (vectorized; NN*HIDDEN = 12.8M, /4 = 3.2M threads exact) ----
__global__ __launch_bounds__(256) void convert_h(
    const float* __restrict__ h, short* __restrict__ h_bf) {
  int i = blockIdx.x * 256 + threadIdx.x;
  f32x4 v = *(const f32x4*)(h + (size_t)i * 4);
  bf16x4 o;
#pragma unroll
  for (int j = 0; j < 4; j++) o[j] = f2bf(v[j]);
  *(bf16x4*)(h_bf + (size_t)i * 4) = o;
}

// ---- 1. global bucket histogram (LDS-aggregated) ----
__global__ __launch_bounds__(256) void part_count(
    const int* __restrict__ esrc, const int* __restrict__ edst,
    int* __restrict__ ghist) {
  __shared__ int lh[NBUCK];
  int tid = threadIdx.x;
  for (int i = tid; i < NBUCK; i += 256) lh[i] = 0;
  __syncthreads();
  int base = blockIdx.x * CHUNK;
  int nit = min(CHUNK, NED - base);
  for (int k = tid; k < nit; k += 256) {
    int ed = base + k;
    int b;
    if (ed < NE) b = esrc[ed] >> 6;
    else b = NBF + (edst[ed - NE] >> 6);
    atomicAdd(&lh[b], 1);
  }
  __syncthreads();
  for (int i = tid; i < NBUCK; i += 256) {
    int c = lh[i];
    if (c) atomicAdd(ghist + i, c);
  }
}

// ---- 2. exclusive scan over ghist[NBUCK] -> bstart (bounds) + gcur (cursors) ----
__global__ __launch_bounds__(1024) void bucket_scan(
    const int* __restrict__ ghist, int* __restrict__ bstart,
    int* __restrict__ gcur) {
  __shared__ int lds[1024];
  __shared__ int carry;
  int tid = threadIdx.x;
  if (tid == 0) carry = 0;
  __syncthreads();
  for (int t = 0; t < 4; t++) {              // 4*1024 >= NBUCK
    int i = t * 1024 + tid;
    int v = (i < NBUCK) ? ghist[i] : 0;
    lds[tid] = v;
    __syncthreads();
    for (int off = 1; off < 1024; off <<= 1) {
      int x = lds[tid];
      int add = (tid >= off) ? lds[tid - off] : 0;
      __syncthreads();
      lds[tid] = x + add;
      __syncthreads();
    }
    int excl = lds[tid] - v + carry;
    if (i < NBUCK) { bstart[i] = excl; gcur[i] = excl; }
    int tot = lds[1023];
    __syncthreads();
    if (tid == 0) carry += tot;
    __syncthreads();
  }
  if (tid == 0) bstart[NBUCK] = carry;   // == NED
}

// ---- 3. radix partition: scatter through LDS, write coalesced runs to ELP ----
// ELP item: (tgt_local<<17) | nbr   (tgt_local<64 -> 6 bits; nbr<100000 -> 17 bits)
// LDS budget trimmed to 3 NBUCK arrays (counts live in lcur, converted to
// cursors after the claim) + CHUNK=4096 staging -> 63KB -> 2 blocks/CU.
__global__ __launch_bounds__(256) void part_scatter(
    const int* __restrict__ esrc, const int* __restrict__ edst,
    int* __restrict__ gcur, unsigned* __restrict__ ELP) {
  __shared__ int lcur[NBUCK];     // counts, then mutable scatter cursors
  __shared__ int loff[NBUCK];     // block-local exclusive offsets (kept intact)
  __shared__ int gbase[NBUCK];    // claimed global run starts
  __shared__ int psum[256];
  __shared__ unsigned buf[CHUNK]; // 16 KB staging
  __shared__ unsigned short bidA[CHUNK];  // 8 KB bucket-id per slot
  int tid = threadIdx.x;
  for (int i = tid; i < NBUCK; i += 256) lcur[i] = 0;
  __syncthreads();
  int base = blockIdx.x * CHUNK;
  int nit = min(CHUNK, NED - base);
  // pass 1: local count (into lcur)
  for (int k = tid; k < nit; k += 256) {
    int ed = base + k;
    int b;
    if (ed < NE) b = esrc[ed] >> 6;
    else b = NBF + (edst[ed - NE] >> 6);
    atomicAdd(&lcur[b], 1);
  }
  __syncthreads();
  // local exclusive scan (PS buckets per thread; PS*256 >= NBUCK)
  int s = 0;
  int lo0 = tid * PS, hi0 = min(NBUCK, tid * PS + PS);
  for (int j = lo0; j < hi0; j++) s += lcur[j];
  psum[tid] = s;
  __syncthreads();
  for (int off = 1; off < 256; off <<= 1) {
    int x = psum[tid];
    int add = (tid >= off) ? psum[tid - off] : 0;
    __syncthreads();
    psum[tid] = x + add;
    __syncthreads();
  }
  int run = psum[tid] - s;
  for (int j = lo0; j < hi0; j++) { loff[j] = run; run += lcur[j]; }
  __syncthreads();
  // claim global runs + convert lcur count -> cursor (each b owned by 1 thread)
  for (int b = tid; b < NBUCK; b += 256) {
    int c = lcur[b];
    if (c) gbase[b] = atomicAdd(gcur + b, c);
    lcur[b] = loff[b];
  }
  __syncthreads();
  // pass 2: scatter into LDS staging, record bucket id per slot
  for (int k = tid; k < nit; k += 256) {
    int ed = base + k;
    int b, tl, nbr;
    if (ed < NE) { int tg = esrc[ed]; nbr = edst[ed]; b = tg >> 6; tl = tg & 63; }
    else { int e = ed - NE; int tg = edst[e]; nbr = esrc[e]; b = NBF + (tg >> 6); tl = tg & 63; }
    int slot = atomicAdd(&lcur[b], 1);
    buf[slot] = ((unsigned)tl << 17) | (unsigned)nbr;
    bidA[slot] = (unsigned short)b;
  }
  __syncthreads();
  // sweep: consecutive lanes -> consecutive slots -> bucket-contiguous global runs
  for (int i = tid; i < nit; i += 256) {
    int b = bidA[i];
    ELP[gbase[b] + (i - loff[b])] = buf[i];
  }
}

// ---- 4. per-bucket counting-sort + chunked stage->accumulate gather ----
// Instead of per-quarter-wave dependent-chain loads (latency-bound), stage
// GC=128 neighbor rows per chunk into LDS with 2048 independent coalesced
// loads per block (8/thread -> latency amortized by bulk MLP), then
// accumulate from LDS (row stride 136 shorts = 272B breaks bank conflicts).
// T14 split: issue next chunk's loads early, accumulate current, write late.
#define ACCU(u, V) { ac[u][0]+=bf2f((V)[0]); ac[u][1]+=bf2f((V)[1]); \
                     ac[u][2]+=bf2f((V)[2]); ac[u][3]+=bf2f((V)[3]); \
                     ac[u][4]+=bf2f((V)[4]); ac[u][5]+=bf2f((V)[5]); \
                     ac[u][6]+=bf2f((V)[6]); ac[u][7]+=bf2f((V)[7]); }
#define MACCU(u, M, V) { ac[u][0]=fmaf(M,bf2f((V)[0]),ac[u][0]); ac[u][1]=fmaf(M,bf2f((V)[1]),ac[u][1]); \
                         ac[u][2]=fmaf(M,bf2f((V)[2]),ac[u][2]); ac[u][3]=fmaf(M,bf2f((V)[3]),ac[u][3]); \
                         ac[u][4]=fmaf(M,bf2f((V)[4]),ac[u][4]); ac[u][5]=fmaf(M,bf2f((V)[5]),ac[u][5]); \
                         ac[u][6]=fmaf(M,bf2f((V)[6]),ac[u][6]); ac[u][7]=fmaf(M,bf2f((V)[7]),ac[u][7]); }
#define LROW(SL) (*(const bf16x8*)(rb + (size_t)((SL) - s0) * 136 + q * 8))
__global__ __launch_bounds__(256, 2) void bucket_gather(
    const short* __restrict__ h_bf, const unsigned* __restrict__ ELP,
    const int* __restrict__ bstart,
    short* __restrict__ aggF, short* __restrict__ aggB,
    int* __restrict__ degFB) {
  __shared__ int sorted[1024];   // bucket mean 512, sigma ~23 -> >20 sigma
  __shared__ int cnt[BKN];
  __shared__ int pfx[BKN];
  __shared__ int cur[BKN];
  __shared__ short rowbuf[2 * GC * 136];   // 69,632 B double-buffered stage
  int tid = threadIdx.x;
  int blk = blockIdx.x;
  int s = bstart[blk], e = bstart[blk + 1], n = e - s;
  if (tid < BKN) cnt[tid] = 0;
  __syncthreads();
  for (int k = tid; k < n; k += 256) atomicAdd(&cnt[ELP[s + k] >> 17], 1);
  __syncthreads();
  // inclusive scan of cnt -> pfx
  int v = (tid < BKN) ? cnt[tid] : 0;
  if (tid < BKN) pfx[tid] = v;
  __syncthreads();
  for (int off = 1; off < BKN; off <<= 1) {
    int add = (tid < BKN && tid >= off) ? pfx[tid - off] : 0;
    __syncthreads();
    if (tid < BKN) pfx[tid] += add;
    __syncthreads();
  }
  if (tid < BKN) cur[tid] = pfx[tid] - cnt[tid];   // exclusive start
  __syncthreads();
  // scatter into sorted-by-node LDS array (store nbr only)
  for (int k = tid; k < n; k += 256) {
    unsigned pv = ELP[s + k];
    int slot = atomicAdd(&cur[pv >> 17], 1);
    sorted[slot] = (int)(pv & 0x1FFFFu);
  }
  __syncthreads();

  int qw = tid >> 4, q = tid & 15;   // quarter-wave id (0..15), lane (0..15)
  // per-thread staging map: pieces p = tid + k*256 -> row = qw + k*16, col = q
  float ac[4][8];
#pragma unroll
  for (int u = 0; u < 4; u++)
#pragma unroll
    for (int j = 0; j < 8; j++) ac[u][j] = 0.f;

  int a0[4], b0[4];
#pragma unroll
  for (int u = 0; u < 4; u++) {
    int nd = qw * 4 + u;
    b0[u] = pfx[nd];
    a0[u] = b0[u] - cnt[nd];
  }

  int nc = (n + GC - 1) / GC;
  bf16x8 st[8];
  if (n > 0) {
    // prologue: stage chunk 0 -> buf 0
#pragma unroll
    for (int k = 0; k < 8; k++) {
      int r = qw + k * 16;
      int nbr = sorted[min(r, n - 1)];       // broadcast ds_read (uniform in qw)
      st[k] = *(const bf16x8*)(h_bf + (size_t)nbr * HIDDEN + q * 8);
    }
#pragma unroll
    for (int k = 0; k < 8; k++) {
      int r = qw + k * 16;
      *(bf16x8*)(rowbuf + r * 136 + q * 8) = st[k];
    }
  }
  __syncthreads();

  for (int c = 0; c < nc; c++) {
    int s0 = c * GC;
    int bsel = c & 1;
    int s1 = s0 + GC;
    int more = (s1 < n);
    if (more) {                              // issue next chunk's loads EARLY
#pragma unroll
      for (int k = 0; k < 8; k++) {
        int r = qw + k * 16;
        int nbr = sorted[min(s1 + r, n - 1)];
        st[k] = *(const bf16x8*)(h_bf + (size_t)nbr * HIDDEN + q * 8);
      }
    }
    // accumulate chunk c from LDS (4-deep, clamped dups masked at tail)
    int cend = min(n, s1);
    const short* rb = rowbuf + bsel * (GC * 136);
#pragma unroll
    for (int u = 0; u < 4; u++) {
      int lo = max(a0[u], s0);
      int hi = min(b0[u], cend);
      if (lo < hi) {
        int lastp = hi - 1;
        bf16x8 v0 = LROW(lo);
        bf16x8 v1 = LROW(min(lo + 1, lastp));
        bf16x8 v2 = LROW(min(lo + 2, lastp));
        bf16x8 v3 = LROW(min(lo + 3, lastp));
        int j = lo;
        while (j + 4 <= hi) {
          ACCU(u, v0); v0 = LROW(min(j + 4, lastp));
          ACCU(u, v1); v1 = LROW(min(j + 5, lastp));
          ACCU(u, v2); v2 = LROW(min(j + 6, lastp));
          ACCU(u, v3); v3 = LROW(min(j + 7, lastp));
          j += 4;
        }
        int rr = hi - j;   // 0..3 remaining (v0..v2 hold clamped rows)
        float m1 = (rr > 0) ? 1.f : 0.f;
        float m2 = (rr > 1) ? 1.f : 0.f;
        float m3 = (rr > 2) ? 1.f : 0.f;
        MACCU(u, m1, v0); MACCU(u, m2, v1); MACCU(u, m3, v2);
      }
    }
    if (more) {                              // write next chunk LATE
      short* wb = rowbuf + (1 - bsel) * (GC * 136);
#pragma unroll
      for (int k = 0; k < 8; k++) {
        int r = qw + k * 16;
        *(bf16x8*)(wb + r * 136 + q * 8) = st[k];
      }
    }
    __syncthreads();
  }

  int dir = blk >= NBF;
  int node0 = (dir ? blk - NBF : blk) * BKN;
  short* agg = dir ? aggB : aggF;
#pragma unroll
  for (int u = 0; u < 4; u++) {
    int node = node0 + qw * 4 + u;
    if (node < NN) {
      bf16x8 o;
      o[0] = f2bf(ac[u][0]); o[1] = f2bf(ac[u][1]);
      o[2] = f2bf(ac[u][2]); o[3] = f2bf(ac[u][3]);
      o[4] = f2bf(ac[u][4]); o[5] = f2bf(ac[u][5]);
      o[6] = f2bf(ac[u][6]); o[7] = f2bf(ac[u][7]);
      *(bf16x8*)(agg + (size_t)node * HIDDEN + q * 8) = o;
    }
  }
  if (tid < BKN) {
    int node = node0 + tid;
    if (node < NN) degFB[dir * NN + node] = cnt[tid];
  }
}

// ---- 5. fused GEMM: register-persistent weights, LDS-streamed activations ----
// out = relu( h@Ws^T + aggF@W^T + aggB@Wt^T + Ws_b + degF*W_b + degB*Wt_b )
// Block = 512 thr = 8 waves; wave w owns cols [w*16, w*16+16) with its 12
// weight fragments register-persistent. Grid-stride over 32-row tiles: stage
// 3x32x128 bf16 activations into LDS (coalesced, +8-short row pad), all 8
// waves share them (8x reuse). mfma(wf, af) computes W·act^T so each lane's 4
// acc elements are 4 consecutive out cols -> one f32x4 store per row-group.
// Staging: 1536 16B-chunks = 512 threads x 3 matrices (row=tid>>4, kc=tid&15).
__global__ __launch_bounds__(512, 4) void gemm_fused(
    const short* __restrict__ h_bf, const short* __restrict__ aggF,
    const short* __restrict__ aggB, const short* __restrict__ Wbf,
    const float* __restrict__ Wb, const float* __restrict__ Wsb,
    const float* __restrict__ Wtb, const int* __restrict__ degFB,
    float* __restrict__ out) {
  __shared__ short At[3 * 32 * 136];   // 26112 B, rows padded 128->136 shorts
  int tid = threadIdx.x;
  int lane = tid & 63;
  int m16 = lane & 15;
  int kq  = lane >> 4;
  int col0 = (tid >> 6) * 16;          // wave's 16-col tile

  // register-persistent weight fragments (one-time scattered loads)
  bf16x8 wf[3][4];
#pragma unroll
  for (int i = 0; i < 3; i++)
#pragma unroll
    for (int t = 0; t < 4; t++)
      wf[i][t] = *(const bf16x8*)(Wbf + i * 16384 + (col0 + m16) * 128 + t * 32 + kq * 8);

  // per-lane bias vectors for out cols col0+kq*4 .. +4 (hoisted)
  f32x4 bW = *(const f32x4*)(Wb  + col0 + kq * 4);
  f32x4 bS = *(const f32x4*)(Wsb + col0 + kq * 4);
  f32x4 bT = *(const f32x4*)(Wtb + col0 + kq * 4);

  // staging map: thread stages chunk (row=tid>>4, kc=tid&15) of each matrix
  int srow = tid >> 4, skc = tid & 15;
  const short* mats[3] = { h_bf, aggF, aggB };
  const short* gbs[3];
  short* lps[3];
#pragma unroll
  for (int k = 0; k < 3; k++) {
    gbs[k] = mats[k] + srow * 128 + skc * 8;
    lps[k] = At + k * 4352 + srow * 136 + skc * 8;
  }

  int tile = blockIdx.x;
  bf16x8 ld[3];
#pragma unroll
  for (int k = 0; k < 3; k++)
    ld[k] = *(const bf16x8*)(gbs[k] + (size_t)tile * 4096);

  while (tile < NTILES) {
    int row0 = tile * 32;
    __syncthreads();                 // previous compute done reading LDS
#pragma unroll
    for (int k = 0; k < 3; k++) *(bf16x8*)lps[k] = ld[k];
    __syncthreads();
    int ntile = tile + gridDim.x;
    if (ntile < NTILES) {            // prefetch next tile during compute
#pragma unroll
      for (int k = 0; k < 3; k++)
        ld[k] = *(const bf16x8*)(gbs[k] + (size_t)ntile * 4096);
    }
#pragma unroll
    for (int g = 0; g < 2; g++) {
      f32x4 acc = {0.f, 0.f, 0.f, 0.f};
      const short* lb = At + (g * 16 + m16) * 136 + kq * 8;
#pragma unroll
      for (int i = 0; i < 3; i++)
#pragma unroll
        for (int t = 0; t < 4; t++) {
          bf16x8 af = *(const bf16x8*)(lb + i * 4352 + t * 32);
          acc = __builtin_amdgcn_mfma_f32_16x16x32_bf16(wf[i][t], af, acc, 0, 0, 0);
        }
      // D lane reg j: out row = row0+g*16+m16, out col = col0+kq*4+j
      int r = row0 + g * 16 + m16;
      float dF = (float)degFB[r];
      float dB = (float)degFB[NN + r];
      f32x4 v;
#pragma unroll
      for (int j = 0; j < 4; j++)
        v[j] = fmaxf(acc[j] + bS[j] + dF * bW[j] + dB * bT[j], 0.f);
      *(f32x4*)(out + (size_t)r * HIDDEN + col0 + kq * 4) = v;
    }
    tile = ntile;
  }
}

extern "C" void kernel_launch(void* const* d_in, const int* in_sizes, int n_in,
                              void* d_out, int out_size, void* d_ws, size_t ws_size,
                              hipStream_t stream) {
  const float* h    = (const float*)d_in[0];
  const int*   esrc = (const int*)d_in[1];
  const int*   edst = (const int*)d_in[2];
  const float* Ww   = (const float*)d_in[3];
  const float* Wb   = (const float*)d_in[4];
  const float* Wsw  = (const float*)d_in[5];
  const float* Wsb  = (const float*)d_in[6];
  const float* Wtw  = (const float*)d_in[7];
  const float* Wtb  = (const float*)d_in[8];
  float* out = (float*)d_out;

  char* ws = (char*)d_ws;
  // byte layout (NBUCK=3126)
  int*      ghist  = (int*)(ws + 0);             //    12,504
  int*      bstart = (int*)(ws + 12544);         //    12,508
  int*      gcur   = (int*)(ws + 25088);         //    12,504  (ends 37,592)
  unsigned* ELP    = (unsigned*)(ws + 37632);    // 6,400,000  (ends 6,437,632)
  short*    Wbf    = (short*)(ws + 6437632);     //    98,304  (ends 6,535,936)
  short*    h_bf   = (short*)(ws + 6535936);     // 25,600,000 (ends 32,135,936)
  short*    aggF   = (short*)(ws + 32135936);    // 25,600,000 (ends 57,735,936)
  short*    aggB   = (short*)(ws + 57735936);    // 25,600,000 (ends 83,335,936)
  int*      degFB  = (int*)(ws + 83335936);      //   800,000  -> total ~84.1 MB

  hipMemsetAsync(ghist, 0, NBUCK * sizeof(int), stream);

  convert_weights<<<192, 256, 0, stream>>>(Wsw, Ww, Wtw, Wbf);
  convert_h<<<12500, 256, 0, stream>>>(h, h_bf);
  part_count<<<PBLK, 256, 0, stream>>>(esrc, edst, ghist);
  bucket_scan<<<1, 1024, 0, stream>>>(ghist, bstart, gcur);
  part_scatter<<<PBLK, 256, 0, stream>>>(esrc, edst, gcur, ELP);
  bucket_gather<<<NBUCK, 256, 0, stream>>>(h_bf, ELP, bstart, aggF, aggB, degFB);
  gemm_fused<<<1024, 512, 0, stream>>>(
      h_bf, aggF, aggB, Wbf, Wb, Wsb, Wtb, degFB, out);
}

// Round 5
// 258.659 us; speedup vs baseline: 1.1554x; 1.1554x over previous
//
#include <hip/hip_runtime.h>
#include <hip/hip_bf16.h>

#define NN 100000
#define NE 800000
#define HIDDEN 128
#define NED (2 * NE)            // edge-directions: [0,NE)=fwd(by src), [NE,2NE)=bwd(by dst)
#define BKN 64                  // nodes per bucket
#define NBF 1563                // ceil(NN/BKN)
#define NBUCK (2 * NBF)         // 3126
#define PS 13                   // buckets per thread in part_scatter scan (13*256>=NBUCK)
#define CHUNK 4096              // edges per partition block (LDS fits 2 blocks/CU)
#define PBLK ((NED + CHUNK - 1) / CHUNK)   // 391
#define NTILES 3125             // 100000 / 32 exact

typedef __attribute__((ext_vector_type(8))) short bf16x8;
typedef __attribute__((ext_vector_type(4))) short bf16x4;
typedef __attribute__((ext_vector_type(4))) float f32x4;

__device__ __forceinline__ short f2bf(float f) {
  union { float f; unsigned u; } x; x.f = f;
  unsigned r = x.u + 0x7fffu + ((x.u >> 16) & 1u);   // RNE
  return (short)(r >> 16);
}
__device__ __forceinline__ float bf2f(short s) {
  union { unsigned u; float f; } x;
  x.u = ((unsigned)(unsigned short)s) << 16;
  return x.f;
}

// ---- weights fp32 -> bf16 (order: [0]=Ws_w, [1]=W_w, [2]=Wt_w) ----
__global__ __launch_bounds__(256) void convert_weights(
    const float* __restrict__ m0, const float* __restrict__ m1,
    const float* __restrict__ m2, short* __restrict__ out) {
  int i = blockIdx.x * 256 + threadIdx.x;   // [0, 3*16384)
  int m = i >> 14, j = i & 16383;
  const float* s = (m == 0) ? m0 : (m == 1) ? m1 : m2;
  out[i] = f2bf(s[j]);
}

// ---- h fp32 -> bf16 (vectorized; NN*HIDDEN = 12.8M, /4 = 3.2M threads exact) ----
__global__ __launch_bounds__(256) void convert_h(
    const float* __restrict__ h, short* __restrict__ h_bf) {
  int i = blockIdx.x * 256 + threadIdx.x;
  f32x4 v = *(const f32x4*)(h + (size_t)i * 4);
  bf16x4 o;
#pragma unroll
  for (int j = 0; j < 4; j++) o[j] = f2bf(v[j]);
  *(bf16x4*)(h_bf + (size_t)i * 4) = o;
}

// ---- 1. global bucket histogram (LDS-aggregated) ----
__global__ __launch_bounds__(256) void part_count(
    const int* __restrict__ esrc, const int* __restrict__ edst,
    int* __restrict__ ghist) {
  __shared__ int lh[NBUCK];
  int tid = threadIdx.x;
  for (int i = tid; i < NBUCK; i += 256) lh[i] = 0;
  __syncthreads();
  int base = blockIdx.x * CHUNK;
  int nit = min(CHUNK, NED - base);
  for (int k = tid; k < nit; k += 256) {
    int ed = base + k;
    int b;
    if (ed < NE) b = esrc[ed] >> 6;
    else b = NBF + (edst[ed - NE] >> 6);
    atomicAdd(&lh[b], 1);
  }
  __syncthreads();
  for (int i = tid; i < NBUCK; i += 256) {
    int c = lh[i];
    if (c) atomicAdd(ghist + i, c);
  }
}

// ---- 2. exclusive scan over ghist[NBUCK] -> bstart + gcur ----
// shfl-based: per-thread 4 vals -> wave scan (no barriers) -> 16 wave sums
// scanned by wave 0 -> 2 barriers total (old version: ~80 barrier rounds).
__global__ __launch_bounds__(1024) void bucket_scan(
    const int* __restrict__ ghist, int* __restrict__ bstart,
    int* __restrict__ gcur) {
  __shared__ int wsum[16];
  __shared__ int woff[16];
  int tid = threadIdx.x;
  int lane = tid & 63, wv = tid >> 6;
  int base = tid * 4;                       // 1024*4 = 4096 >= NBUCK
  int v0 = (base + 0 < NBUCK) ? ghist[base + 0] : 0;
  int v1 = (base + 1 < NBUCK) ? ghist[base + 1] : 0;
  int v2 = (base + 2 < NBUCK) ? ghist[base + 2] : 0;
  int v3 = (base + 3 < NBUCK) ? ghist[base + 3] : 0;
  int s = v0 + v1 + v2 + v3;
  int inc = s;                              // wave-inclusive scan of s
#pragma unroll
  for (int d = 1; d < 64; d <<= 1) {
    int t = __shfl_up(inc, d, 64);
    if (lane >= d) inc += t;
  }
  if (lane == 63) wsum[wv] = inc;
  __syncthreads();
  if (wv == 0) {
    int x = (lane < 16) ? wsum[lane] : 0;
    int i2 = x;
#pragma unroll
    for (int d = 1; d < 16; d <<= 1) {
      int t = __shfl_up(i2, d, 64);
      if (lane >= d) i2 += t;
    }
    if (lane < 16) woff[lane] = i2 - x;     // exclusive wave offset
  }
  __syncthreads();
  int e = woff[wv] + inc - s;               // exclusive prefix for base+0
  if (base + 0 < NBUCK) { bstart[base + 0] = e; gcur[base + 0] = e; }
  e += v0;
  if (base + 1 < NBUCK) { bstart[base + 1] = e; gcur[base + 1] = e; }
  e += v1;
  if (base + 2 < NBUCK) { bstart[base + 2] = e; gcur[base + 2] = e; }
  e += v2;
  if (base + 3 < NBUCK) { bstart[base + 3] = e; gcur[base + 3] = e; }
  e += v3;
  if (tid == 1023) bstart[NBUCK] = e;       // grand total == NED
}

// ---- 3. radix partition: scatter through LDS, write coalesced runs to ELP ----
// ELP item: (tgt_local<<17) | nbr   (tgt_local<64 -> 6 bits; nbr<100000 -> 17 bits)
// LDS budget: 3 NBUCK arrays (counts live in lcur, converted to cursors after
// the claim) + CHUNK=4096 staging -> 63KB -> 2 blocks/CU. [round-4 win: ~22us]
__global__ __launch_bounds__(256) void part_scatter(
    const int* __restrict__ esrc, const int* __restrict__ edst,
    int* __restrict__ gcur, unsigned* __restrict__ ELP) {
  __shared__ int lcur[NBUCK];     // counts, then mutable scatter cursors
  __shared__ int loff[NBUCK];     // block-local exclusive offsets (kept intact)
  __shared__ int gbase[NBUCK];    // claimed global run starts
  __shared__ int psum[256];
  __shared__ unsigned buf[CHUNK]; // 16 KB staging
  __shared__ unsigned short bidA[CHUNK];  // 8 KB bucket-id per slot
  int tid = threadIdx.x;
  for (int i = tid; i < NBUCK; i += 256) lcur[i] = 0;
  __syncthreads();
  int base = blockIdx.x * CHUNK;
  int nit = min(CHUNK, NED - base);
  // pass 1: local count (into lcur)
  for (int k = tid; k < nit; k += 256) {
    int ed = base + k;
    int b;
    if (ed < NE) b = esrc[ed] >> 6;
    else b = NBF + (edst[ed - NE] >> 6);
    atomicAdd(&lcur[b], 1);
  }
  __syncthreads();
  // local exclusive scan (PS buckets per thread; PS*256 >= NBUCK)
  int s = 0;
  int lo0 = tid * PS, hi0 = min(NBUCK, tid * PS + PS);
  for (int j = lo0; j < hi0; j++) s += lcur[j];
  psum[tid] = s;
  __syncthreads();
  for (int off = 1; off < 256; off <<= 1) {
    int x = psum[tid];
    int add = (tid >= off) ? psum[tid - off] : 0;
    __syncthreads();
    psum[tid] = x + add;
    __syncthreads();
  }
  int run = psum[tid] - s;
  for (int j = lo0; j < hi0; j++) { loff[j] = run; run += lcur[j]; }
  __syncthreads();
  // claim global runs + convert lcur count -> cursor (each b owned by 1 thread)
  for (int b = tid; b < NBUCK; b += 256) {
    int c = lcur[b];
    if (c) gbase[b] = atomicAdd(gcur + b, c);
    lcur[b] = loff[b];
  }
  __syncthreads();
  // pass 2: scatter into LDS staging, record bucket id per slot
  for (int k = tid; k < nit; k += 256) {
    int ed = base + k;
    int b, tl, nbr;
    if (ed < NE) { int tg = esrc[ed]; nbr = edst[ed]; b = tg >> 6; tl = tg & 63; }
    else { int e = ed - NE; int tg = edst[e]; nbr = esrc[e]; b = NBF + (tg >> 6); tl = tg & 63; }
    int slot = atomicAdd(&lcur[b], 1);
    buf[slot] = ((unsigned)tl << 17) | (unsigned)nbr;
    bidA[slot] = (unsigned short)b;
  }
  __syncthreads();
  // sweep: consecutive lanes -> consecutive slots -> bucket-contiguous global runs
  for (int i = tid; i < nit; i += 256) {
    int b = bidA[i];
    ELP[gbase[b] + (i - loff[b])] = buf[i];
  }
}

// ---- 4. per-bucket counting-sort + register-accumulated gather ----
// [round-2 version, measured 64us] Quarter-wave (16 lanes x 16B = one 256B
// row) per node, 4 nodes per quarter-wave. Depth-4 row pipeline: v0..v3 rows
// in flight, indices prefetched one group ahead (ds latency hidden), clamped
// prefetch dups are L1 hits and never accumulated.
#define ACC8(V) { a0f+=bf2f((V)[0]); a1f+=bf2f((V)[1]); a2f+=bf2f((V)[2]); a3f+=bf2f((V)[3]); \
                  a4f+=bf2f((V)[4]); a5f+=bf2f((V)[5]); a6f+=bf2f((V)[6]); a7f+=bf2f((V)[7]); }
#define MACC8(M,V) { a0f=fmaf(M,bf2f((V)[0]),a0f); a1f=fmaf(M,bf2f((V)[1]),a1f); \
                     a2f=fmaf(M,bf2f((V)[2]),a2f); a3f=fmaf(M,bf2f((V)[3]),a3f); \
                     a4f=fmaf(M,bf2f((V)[4]),a4f); a5f=fmaf(M,bf2f((V)[5]),a5f); \
                     a6f=fmaf(M,bf2f((V)[6]),a6f); a7f=fmaf(M,bf2f((V)[7]),a7f); }
__global__ __launch_bounds__(256, 6) void bucket_gather(
    const short* __restrict__ h_bf, const unsigned* __restrict__ ELP,
    const int* __restrict__ bstart,
    short* __restrict__ aggF, short* __restrict__ aggB,
    int* __restrict__ degFB) {
  __shared__ int sorted[1024];   // bucket mean 512, sigma ~23 -> >20 sigma
  __shared__ int cnt[BKN];
  __shared__ int pfx[BKN];
  __shared__ int cur[BKN];
  int tid = threadIdx.x;
  int blk = blockIdx.x;
  int s = bstart[blk], e = bstart[blk + 1], n = e - s;
  if (tid < BKN) cnt[tid] = 0;
  __syncthreads();
  for (int k = tid; k < n; k += 256) atomicAdd(&cnt[ELP[s + k] >> 17], 1);
  __syncthreads();
  // inclusive scan of cnt -> pfx
  int v = (tid < BKN) ? cnt[tid] : 0;
  if (tid < BKN) pfx[tid] = v;
  __syncthreads();
  for (int off = 1; off < BKN; off <<= 1) {
    int add = (tid < BKN && tid >= off) ? pfx[tid - off] : 0;
    __syncthreads();
    if (tid < BKN) pfx[tid] += add;
    __syncthreads();
  }
  if (tid < BKN) cur[tid] = pfx[tid] - cnt[tid];   // exclusive start
  __syncthreads();
  // scatter into sorted-by-node LDS array (store nbr only)
  for (int k = tid; k < n; k += 256) {
    unsigned pv = ELP[s + k];
    int slot = atomicAdd(&cur[pv >> 17], 1);
    sorted[slot] = (int)(pv & 0x1FFFFu);
  }
  __syncthreads();
  // gather
  int dir = blk >= NBF;
  int node0 = (dir ? blk - NBF : blk) * BKN;
  short* agg = dir ? aggB : aggF;
  int qw = tid >> 4, q = tid & 15;
  const short* hb = h_bf + (size_t)q * 8;      // lane's 16B column slice
#pragma unroll
  for (int t = 0; t < 4; t++) {
    int nd = qw * 4 + t;
    int b0 = pfx[nd];
    int deg = cnt[nd];
    int a0 = b0 - deg;
    float a0f = 0.f, a1f = 0.f, a2f = 0.f, a3f = 0.f;
    float a4f = 0.f, a5f = 0.f, a6f = 0.f, a7f = 0.f;
    if (deg > 0) {
      int lastp = b0 - 1;
      int i0 = sorted[a0];
      int i1 = sorted[min(a0 + 1, lastp)];
      int i2 = sorted[min(a0 + 2, lastp)];
      int i3 = sorted[min(a0 + 3, lastp)];
      bf16x8 v0 = *(const bf16x8*)(hb + (size_t)i0 * HIDDEN);
      bf16x8 v1 = *(const bf16x8*)(hb + (size_t)i1 * HIDDEN);
      bf16x8 v2 = *(const bf16x8*)(hb + (size_t)i2 * HIDDEN);
      bf16x8 v3 = *(const bf16x8*)(hb + (size_t)i3 * HIDDEN);
      int j = a0;
      int ni0 = sorted[min(j + 4, lastp)];
      int ni1 = sorted[min(j + 5, lastp)];
      int ni2 = sorted[min(j + 6, lastp)];
      int ni3 = sorted[min(j + 7, lastp)];
      while (j + 4 <= b0) {
        ACC8(v0); v0 = *(const bf16x8*)(hb + (size_t)ni0 * HIDDEN);
        ACC8(v1); v1 = *(const bf16x8*)(hb + (size_t)ni1 * HIDDEN);
        ACC8(v2); v2 = *(const bf16x8*)(hb + (size_t)ni2 * HIDDEN);
        ACC8(v3); v3 = *(const bf16x8*)(hb + (size_t)ni3 * HIDDEN);
        j += 4;
        ni0 = sorted[min(j + 4, lastp)];
        ni1 = sorted[min(j + 5, lastp)];
        ni2 = sorted[min(j + 6, lastp)];
        ni3 = sorted[min(j + 7, lastp)];
      }
      int r = b0 - j;   // 0..3 remaining; v0..v2 hold edges j..j+2 (clamped dups)
      float m1 = (r > 0) ? 1.f : 0.f;
      float m2 = (r > 1) ? 1.f : 0.f;
      float m3 = (r > 2) ? 1.f : 0.f;
      MACC8(m1, v0); MACC8(m2, v1); MACC8(m3, v2);
    }
    int node = node0 + nd;
    if (node < NN) {
      bf16x8 o;
      o[0] = f2bf(a0f); o[1] = f2bf(a1f); o[2] = f2bf(a2f); o[3] = f2bf(a3f);
      o[4] = f2bf(a4f); o[5] = f2bf(a5f); o[6] = f2bf(a6f); o[7] = f2bf(a7f);
      *(bf16x8*)(agg + (size_t)node * HIDDEN + q * 8) = o;
    }
  }
  if (tid < BKN) {
    int node = node0 + tid;
    if (node < NN) degFB[dir * NN + node] = cnt[tid];
  }
}

// ---- 5. fused GEMM: register-persistent weights, LDS-streamed activations ----
// out = relu( h@Ws^T + aggF@W^T + aggB@Wt^T + Ws_b + degF*W_b + degB*Wt_b )
// Block = 512 thr = 8 waves; wave w owns cols [w*16, w*16+16) with its 12
// weight fragments register-persistent. Grid-stride over 32-row tiles: stage
// 3x32x128 bf16 activations into LDS (coalesced, +8-short row pad), all 8
// waves share them (8x reuse). mfma(wf, af) computes W·act^T so each lane's 4
// acc elements are 4 consecutive out cols -> one f32x4 store per row-group.
// Staging: 1536 16B-chunks = 512 threads x 3 matrices (row=tid>>4, kc=tid&15).
__global__ __launch_bounds__(512, 4) void gemm_fused(
    const short* __restrict__ h_bf, const short* __restrict__ aggF,
    const short* __restrict__ aggB, const short* __restrict__ Wbf,
    const float* __restrict__ Wb, const float* __restrict__ Wsb,
    const float* __restrict__ Wtb, const int* __restrict__ degFB,
    float* __restrict__ out) {
  __shared__ short At[3 * 32 * 136];   // 26112 B, rows padded 128->136 shorts
  int tid = threadIdx.x;
  int lane = tid & 63;
  int m16 = lane & 15;
  int kq  = lane >> 4;
  int col0 = (tid >> 6) * 16;          // wave's 16-col tile

  // register-persistent weight fragments (one-time scattered loads)
  bf16x8 wf[3][4];
#pragma unroll
  for (int i = 0; i < 3; i++)
#pragma unroll
    for (int t = 0; t < 4; t++)
      wf[i][t] = *(const bf16x8*)(Wbf + i * 16384 + (col0 + m16) * 128 + t * 32 + kq * 8);

  // per-lane bias vectors for out cols col0+kq*4 .. +4 (hoisted)
  f32x4 bW = *(const f32x4*)(Wb  + col0 + kq * 4);
  f32x4 bS = *(const f32x4*)(Wsb + col0 + kq * 4);
  f32x4 bT = *(const f32x4*)(Wtb + col0 + kq * 4);

  // staging map: thread stages chunk (row=tid>>4, kc=tid&15) of each matrix
  int srow = tid >> 4, skc = tid & 15;
  const short* mats[3] = { h_bf, aggF, aggB };
  const short* gbs[3];
  short* lps[3];
#pragma unroll
  for (int k = 0; k < 3; k++) {
    gbs[k] = mats[k] + srow * 128 + skc * 8;
    lps[k] = At + k * 4352 + srow * 136 + skc * 8;
  }

  int tile = blockIdx.x;
  bf16x8 ld[3];
#pragma unroll
  for (int k = 0; k < 3; k++)
    ld[k] = *(const bf16x8*)(gbs[k] + (size_t)tile * 4096);

  while (tile < NTILES) {
    int row0 = tile * 32;
    __syncthreads();                 // previous compute done reading LDS
#pragma unroll
    for (int k = 0; k < 3; k++) *(bf16x8*)lps[k] = ld[k];
    __syncthreads();
    int ntile = tile + gridDim.x;
    if (ntile < NTILES) {            // prefetch next tile during compute
#pragma unroll
      for (int k = 0; k < 3; k++)
        ld[k] = *(const bf16x8*)(gbs[k] + (size_t)ntile * 4096);
    }
#pragma unroll
    for (int g = 0; g < 2; g++) {
      f32x4 acc = {0.f, 0.f, 0.f, 0.f};
      const short* lb = At + (g * 16 + m16) * 136 + kq * 8;
#pragma unroll
      for (int i = 0; i < 3; i++)
#pragma unroll
        for (int t = 0; t < 4; t++) {
          bf16x8 af = *(const bf16x8*)(lb + i * 4352 + t * 32);
          acc = __builtin_amdgcn_mfma_f32_16x16x32_bf16(wf[i][t], af, acc, 0, 0, 0);
        }
      // D lane reg j: out row = row0+g*16+m16, out col = col0+kq*4+j
      int r = row0 + g * 16 + m16;
      float dF = (float)degFB[r];
      float dB = (float)degFB[NN + r];
      f32x4 v;
#pragma unroll
      for (int j = 0; j < 4; j++)
        v[j] = fmaxf(acc[j] + bS[j] + dF * bW[j] + dB * bT[j], 0.f);
      *(f32x4*)(out + (size_t)r * HIDDEN + col0 + kq * 4) = v;
    }
    tile = ntile;
  }
}

extern "C" void kernel_launch(void* const* d_in, const int* in_sizes, int n_in,
                              void* d_out, int out_size, void* d_ws, size_t ws_size,
                              hipStream_t stream) {
  const float* h    = (const float*)d_in[0];
  const int*   esrc = (const int*)d_in[1];
  const int*   edst = (const int*)d_in[2];
  const float* Ww   = (const float*)d_in[3];
  const float* Wb   = (const float*)d_in[4];
  const float* Wsw  = (const float*)d_in[5];
  const float* Wsb  = (const float*)d_in[6];
  const float* Wtw  = (const float*)d_in[7];
  const float* Wtb  = (const float*)d_in[8];
  float* out = (float*)d_out;

  char* ws = (char*)d_ws;
  // byte layout (NBUCK=3126)
  int*      ghist  = (int*)(ws + 0);             //    12,504
  int*      bstart = (int*)(ws + 12544);         //    12,508
  int*      gcur   = (int*)(ws + 25088);         //    12,504  (ends 37,592)
  unsigned* ELP    = (unsigned*)(ws + 37632);    // 6,400,000  (ends 6,437,632)
  short*    Wbf    = (short*)(ws + 6437632);     //    98,304  (ends 6,535,936)
  short*    h_bf   = (short*)(ws + 6535936);     // 25,600,000 (ends 32,135,936)
  short*    aggF   = (short*)(ws + 32135936);    // 25,600,000 (ends 57,735,936)
  short*    aggB   = (short*)(ws + 57735936);    // 25,600,000 (ends 83,335,936)
  int*      degFB  = (int*)(ws + 83335936);      //   800,000  -> total ~84.1 MB

  hipMemsetAsync(ghist, 0, NBUCK * sizeof(int), stream);

  convert_weights<<<192, 256, 0, stream>>>(Wsw, Ww, Wtw, Wbf);
  convert_h<<<12500, 256, 0, stream>>>(h, h_bf);
  part_count<<<PBLK, 256, 0, stream>>>(esrc, edst, ghist);
  bucket_scan<<<1, 1024, 0, stream>>>(ghist, bstart, gcur);
  part_scatter<<<PBLK, 256, 0, stream>>>(esrc, edst, gcur, ELP);
  bucket_gather<<<NBUCK, 256, 0, stream>>>(h_bf, ELP, bstart, aggF, aggB, degFB);
  gemm_fused<<<1024, 512, 0, stream>>>(
      h_bf, aggF, aggB, Wbf, Wb, Wsb, Wtb, degFB, out);
}